// Round 2
// baseline (3187.254 us; speedup 1.0000x reference)
//
#include <hip/hip_runtime.h>
#include <hip/hip_bf16.h>
#include <math.h>

// LSTM language model, fp32 baseline (round 1: inputs are int32, not int64 —
// JAX default has x64 disabled; harness passes int32).
// ws layout (~57 MB):
//   xWb  [128][16][4096] f32   33,554,432 B @ 0
//   hsx  [129][16][1024] f32    8,454,144 B @ 33,554,432   (slot 0 = h0 = 0)
//   cbuf [16][1024]      f32       65,536 B @ 42,008,576
//   Ut   [4096][1024]    f32   16,777,216 B @ 42,074,112

#define VOCAB 32000
#define EMBED 256
#define UNITS 1024
#define GATES 4096
#define BATCH 16
#define SEQ 128

// ---------- K0: transpose U [1024][4096] -> Ut [4096][1024] ----------
__global__ void k_transposeU(const float* __restrict__ U, float* __restrict__ Ut) {
    __shared__ float tile[32][33];
    const int bx = blockIdx.x;            // col tile (4096/32 = 128)
    const int by = blockIdx.y;            // k   tile (1024/32 = 32)
    const int tx = threadIdx.x & 31;
    const int ty = threadIdx.x >> 5;      // 0..7
    const int col = bx * 32 + tx;
    for (int i = ty; i < 32; i += 8) {
        int k = by * 32 + i;
        tile[i][tx] = U[(size_t)k * GATES + col];
    }
    __syncthreads();
    const int k2 = by * 32 + tx;
    for (int i = ty; i < 32; i += 8) {
        int col2 = bx * 32 + i;
        Ut[(size_t)col2 * UNITS + k2] = tile[tx][i];
    }
}

// ---------- K1: xWb[t][b][col] = emb[inputs[b][t]] @ W + bias ----------
__global__ void k_embed_xw(const int* __restrict__ inputs,
                           const float* __restrict__ emb,
                           const float* __restrict__ W,
                           const float* __restrict__ bias,
                           float* __restrict__ xWb) {
    const int t   = blockIdx.y;                       // 0..127
    const int col = blockIdx.x * 256 + threadIdx.x;   // 0..4095
    __shared__ float xs[BATCH][EMBED];                // 16 KB
    __shared__ int   toks[BATCH];
    if (threadIdx.x < BATCH)
        toks[threadIdx.x] = inputs[threadIdx.x * SEQ + t];
    __syncthreads();
    for (int r = 0; r < BATCH; ++r)
        xs[r][threadIdx.x] = emb[(size_t)toks[r] * EMBED + threadIdx.x];
    __syncthreads();
    float acc[BATCH];
#pragma unroll
    for (int r = 0; r < BATCH; ++r) acc[r] = 0.f;
    for (int k = 0; k < EMBED; ++k) {
        float w = W[(size_t)k * GATES + col];
#pragma unroll
        for (int r = 0; r < BATCH; ++r) acc[r] += xs[r][k] * w;
    }
    const float bb = bias[col];
#pragma unroll
    for (int r = 0; r < BATCH; ++r)
        xWb[((size_t)t * BATCH + r) * GATES + col] = acc[r] + bb;
}

// ---------- K2: one LSTM step ----------
// 256 blocks x 256 threads. Block owns j0..j0+3 (4 hidden cells), i.e. the 16
// gate columns {g*1024 + j0 + dj}. c update is block-local; h goes to hsx[t+1].
__global__ void __launch_bounds__(256) k_lstm_step(
    int t,
    const float* __restrict__ Ut,
    const float* __restrict__ xWb,
    float* __restrict__ hsx,
    float* __restrict__ cbuf) {
    __shared__ float hls[BATCH * UNITS];     // 64 KB, k-swizzled
    __shared__ float red[16][16][17];        // [kchunk][lc][b] (~17 KB)
    __shared__ float zf[16][16];             // [lc][b]
    const int tid = threadIdx.x;

    // stage h_prev (= hsx slot t) into LDS; swizzle k bits [3:2] ^= bits [7:6]
    const float* hprev = hsx + (size_t)t * BATCH * UNITS;
    for (int i = tid * 4; i < BATCH * UNITS; i += 256 * 4) {
        float4 v = *(const float4*)(hprev + i);
        int b = i >> 10, k = i & 1023;
        int ks = k ^ ((((k >> 6) & 3)) << 2);
        *(float4*)(&hls[(b << 10) | ks]) = v;
    }
    __syncthreads();

    const int lc = tid & 15;            // local col 0..15
    const int kc = tid >> 4;            // k-chunk 0..15 (64 k each)
    const int j0 = blockIdx.x * 4;
    const int col = (lc >> 2) * UNITS + j0 + (lc & 3);
    const float* up = Ut + (size_t)col * UNITS + kc * 64;

    float acc[BATCH];
#pragma unroll
    for (int b = 0; b < BATCH; ++b) acc[b] = 0.f;
#pragma unroll
    for (int kk4 = 0; kk4 < 16; ++kk4) {
        float4 u4 = *(const float4*)(up + kk4 * 4);
        int kbase = kc * 64 + kk4 * 4;
        int ks = kbase ^ ((kc & 3) << 2);
#pragma unroll
        for (int b = 0; b < BATCH; ++b) {
            float4 h4 = *(const float4*)(&hls[(b << 10) | ks]);
            acc[b] += u4.x * h4.x + u4.y * h4.y + u4.z * h4.z + u4.w * h4.w;
        }
    }
#pragma unroll
    for (int b = 0; b < BATCH; ++b) red[kc][lc][b] = acc[b];
    __syncthreads();

    // reduce over k-chunks: thread (lc2, b2)
    const int b2 = tid & 15, lc2 = tid >> 4;
    float z = 0.f;
#pragma unroll
    for (int k = 0; k < 16; ++k) z += red[k][lc2][b2];
    const int col2 = (lc2 >> 2) * UNITS + j0 + (lc2 & 3);
    z += xWb[((size_t)t * BATCH + b2) * GATES + col2];
    zf[lc2][b2] = z;
    __syncthreads();

    if (tid < 64) {
        const int b = tid & 15, dj = tid >> 4;   // dj 0..3
        const int j = j0 + dj;
        float zi = zf[0 * 4 + dj][b];
        float zff = zf[1 * 4 + dj][b];
        float zg = zf[2 * 4 + dj][b];
        float zo = zf[3 * 4 + dj][b];
        float c_old = cbuf[b * UNITS + j];
        float si = 1.f / (1.f + expf(-zi));
        float sf = 1.f / (1.f + expf(-zff));
        float so = 1.f / (1.f + expf(-zo));
        float c_new = sf * c_old + si * tanhf(zg);
        float h_new = so * tanhf(c_new);
        cbuf[b * UNITS + j] = c_new;
        hsx[((size_t)(t + 1) * BATCH + b) * UNITS + j] = h_new;
    }
}

// ---------- K3: logits[n][v] = hs[n] @ Wc + bc, n = b*128 + t ----------
// 128x128 tile, 256 threads, 8x8 micro-tile per thread, k-tile = 8.
__global__ void __launch_bounds__(256) k_proj(
    const float* __restrict__ hsx,
    const float* __restrict__ Wc,
    const float* __restrict__ bc,
    float* __restrict__ out) {
    __shared__ float As[8][128];
    __shared__ float Bs[8][128];
    const int tid = threadIdx.x;
    const int n0 = blockIdx.x * 128;
    const int m0 = blockIdx.y * 128;

    // A loader: row am (out-row order), 4 k's per thread
    const int am = m0 + (tid >> 1);
    const int t_ = am & 127, b_ = am >> 7;
    const float* arow = hsx + ((size_t)(t_ + 1) * BATCH + b_) * UNITS;
    const int ak0 = (tid & 1) * 4;
    // B loader: kk = tid>>5 (0..7), n = n0 + (tid&31)*4
    const float* bp = Wc + (size_t)(tid >> 5) * VOCAB + n0 + (tid & 31) * 4;

    const int tx = tid & 15, ty = tid >> 4;
    float accum[8][8];
#pragma unroll
    for (int i = 0; i < 8; ++i)
#pragma unroll
        for (int j = 0; j < 8; ++j) accum[i][j] = 0.f;

    for (int k0 = 0; k0 < UNITS; k0 += 8) {
        float4 a4 = *(const float4*)(arow + k0 + ak0);
        float4 b4 = *(const float4*)(bp + (size_t)k0 * VOCAB);
        __syncthreads();
        As[ak0 + 0][tid >> 1] = a4.x;
        As[ak0 + 1][tid >> 1] = a4.y;
        As[ak0 + 2][tid >> 1] = a4.z;
        As[ak0 + 3][tid >> 1] = a4.w;
        *(float4*)(&Bs[tid >> 5][(tid & 31) * 4]) = b4;
        __syncthreads();
#pragma unroll
        for (int kk = 0; kk < 8; ++kk) {
            float a[8], bb[8];
            *(float4*)&a[0]  = *(const float4*)(&As[kk][ty * 8]);
            *(float4*)&a[4]  = *(const float4*)(&As[kk][ty * 8 + 4]);
            *(float4*)&bb[0] = *(const float4*)(&Bs[kk][tx * 8]);
            *(float4*)&bb[4] = *(const float4*)(&Bs[kk][tx * 8 + 4]);
#pragma unroll
            for (int i = 0; i < 8; ++i)
#pragma unroll
                for (int j = 0; j < 8; ++j) accum[i][j] += a[i] * bb[j];
        }
    }

    float bcv[8];
#pragma unroll
    for (int j = 0; j < 8; ++j) bcv[j] = bc[n0 + tx * 8 + j];
#pragma unroll
    for (int i = 0; i < 8; ++i) {
        const int m = m0 + ty * 8 + i;
        float* op = out + (size_t)m * VOCAB + n0 + tx * 8;
        float4 v0 = make_float4(accum[i][0] + bcv[0], accum[i][1] + bcv[1],
                                accum[i][2] + bcv[2], accum[i][3] + bcv[3]);
        float4 v1 = make_float4(accum[i][4] + bcv[4], accum[i][5] + bcv[5],
                                accum[i][6] + bcv[6], accum[i][7] + bcv[7]);
        *(float4*)(op + 0) = v0;
        *(float4*)(op + 4) = v1;
    }
}

extern "C" void kernel_launch(void* const* d_in, const int* in_sizes, int n_in,
                              void* d_out, int out_size, void* d_ws, size_t ws_size,
                              hipStream_t stream) {
    const int*   inputs = (const int*)d_in[0];   // int32 (JAX x64 disabled)
    const float* emb  = (const float*)d_in[1];
    const float* W    = (const float*)d_in[2];
    const float* U    = (const float*)d_in[3];
    const float* bias = (const float*)d_in[4];
    const float* Wc   = (const float*)d_in[5];
    const float* bc   = (const float*)d_in[6];
    float* out = (float*)d_out;

    char* ws = (char*)d_ws;
    float* xWb  = (float*)(ws + 0);
    float* hsx  = (float*)(ws + 33554432);
    float* cbuf = (float*)(ws + 42008576);
    float* Ut   = (float*)(ws + 42074112);

    // h0 = 0, c0 = 0 (must re-zero every call: deterministic)
    hipMemsetAsync(hsx,  0, (size_t)BATCH * UNITS * 4, stream);
    hipMemsetAsync(cbuf, 0, (size_t)BATCH * UNITS * 4, stream);

    k_transposeU<<<dim3(128, 32), 256, 0, stream>>>(U, Ut);
    k_embed_xw<<<dim3(16, 128), 256, 0, stream>>>(inputs, emb, W, bias, xWb);
    for (int t = 0; t < SEQ; ++t)
        k_lstm_step<<<256, 256, 0, stream>>>(t, Ut, xWb, hsx, cbuf);
    k_proj<<<dim3(250, 16), 256, 0, stream>>>(hsx, Wc, bc, out);
}

// Round 3
// 2061.022 us; speedup vs baseline: 1.5464x; 1.5464x over previous
//
#include <hip/hip_runtime.h>
#include <hip/hip_bf16.h>
#include <math.h>

// LSTM language model. Round 3: projection GEMM -> bf16 hi/lo 3-pass MFMA.
// ws layout (~59 MB):
//   xWb  [128][16][4096] f32   33,554,432 B @ 0
//   hsx  [129][16][1024] f32    8,454,144 B @ 33,554,432   (slot 0 = h0 = 0)
//   cbuf [16][1024]      f32       65,536 B @ 42,008,576
//   Ut   [4096][1024]    f32   16,777,216 B @ 42,074,112

#define VOCAB 32000
#define EMBED 256
#define UNITS 1024
#define GATES 4096
#define BATCH 16
#define SEQ 128

using s16x8 = __attribute__((ext_vector_type(8))) short;
using f32x4 = __attribute__((ext_vector_type(4))) float;

__device__ __forceinline__ unsigned short bf16_rne(float x) {
    unsigned u = __builtin_bit_cast(unsigned, x);
    unsigned r = u + 0x7FFFu + ((u >> 16) & 1u);
    return (unsigned short)(r >> 16);
}
__device__ __forceinline__ float bf16_f32(unsigned short h) {
    unsigned u = ((unsigned)h) << 16;
    return __builtin_bit_cast(float, u);
}
__device__ __forceinline__ unsigned short bf16_trunc(float x) {
    return (unsigned short)(__builtin_bit_cast(unsigned, x) >> 16);
}
// swizzled element index into a [rows][64] ushort LDS tile (row-major).
// XOR bits 3..5 of the element index with a row hash -> frag reads 2-way (free).
__device__ __forceinline__ int swz_e(int r, int k) {
    return (r * 64 + k) ^ ((((r & 7) ^ ((r >> 2) & 7))) << 3);
}

// ---------- K0: transpose U [1024][4096] -> Ut [4096][1024] ----------
__global__ void k_transposeU(const float* __restrict__ U, float* __restrict__ Ut) {
    __shared__ float tile[32][33];
    const int bx = blockIdx.x;
    const int by = blockIdx.y;
    const int tx = threadIdx.x & 31;
    const int ty = threadIdx.x >> 5;
    const int col = bx * 32 + tx;
    for (int i = ty; i < 32; i += 8) {
        int k = by * 32 + i;
        tile[i][tx] = U[(size_t)k * GATES + col];
    }
    __syncthreads();
    const int k2 = by * 32 + tx;
    for (int i = ty; i < 32; i += 8) {
        int col2 = bx * 32 + i;
        Ut[(size_t)col2 * UNITS + k2] = tile[tx][i];
    }
}

// ---------- K1: xWb[t][b][col] = emb[inputs[b][t]] @ W + bias ----------
__global__ void k_embed_xw(const int* __restrict__ inputs,
                           const float* __restrict__ emb,
                           const float* __restrict__ W,
                           const float* __restrict__ bias,
                           float* __restrict__ xWb) {
    const int t   = blockIdx.y;
    const int col = blockIdx.x * 256 + threadIdx.x;
    __shared__ float xs[BATCH][EMBED];
    __shared__ int   toks[BATCH];
    if (threadIdx.x < BATCH)
        toks[threadIdx.x] = inputs[threadIdx.x * SEQ + t];
    __syncthreads();
    for (int r = 0; r < BATCH; ++r)
        xs[r][threadIdx.x] = emb[(size_t)toks[r] * EMBED + threadIdx.x];
    __syncthreads();
    float acc[BATCH];
#pragma unroll
    for (int r = 0; r < BATCH; ++r) acc[r] = 0.f;
    for (int k = 0; k < EMBED; ++k) {
        float w = W[(size_t)k * GATES + col];
#pragma unroll
        for (int r = 0; r < BATCH; ++r) acc[r] += xs[r][k] * w;
    }
    const float bb = bias[col];
#pragma unroll
    for (int r = 0; r < BATCH; ++r)
        xWb[((size_t)t * BATCH + r) * GATES + col] = acc[r] + bb;
}

// ---------- K2: one LSTM step (unchanged this round) ----------
__global__ void __launch_bounds__(256) k_lstm_step(
    int t,
    const float* __restrict__ Ut,
    const float* __restrict__ xWb,
    float* __restrict__ hsx,
    float* __restrict__ cbuf) {
    __shared__ float hls[BATCH * UNITS];
    __shared__ float red[16][16][17];
    __shared__ float zf[16][16];
    const int tid = threadIdx.x;

    const float* hprev = hsx + (size_t)t * BATCH * UNITS;
    for (int i = tid * 4; i < BATCH * UNITS; i += 256 * 4) {
        float4 v = *(const float4*)(hprev + i);
        int b = i >> 10, k = i & 1023;
        int ks = k ^ ((((k >> 6) & 3)) << 2);
        *(float4*)(&hls[(b << 10) | ks]) = v;
    }
    __syncthreads();

    const int lc = tid & 15;
    const int kc = tid >> 4;
    const int j0 = blockIdx.x * 4;
    const int col = (lc >> 2) * UNITS + j0 + (lc & 3);
    const float* up = Ut + (size_t)col * UNITS + kc * 64;

    float acc[BATCH];
#pragma unroll
    for (int b = 0; b < BATCH; ++b) acc[b] = 0.f;
#pragma unroll
    for (int kk4 = 0; kk4 < 16; ++kk4) {
        float4 u4 = *(const float4*)(up + kk4 * 4);
        int kbase = kc * 64 + kk4 * 4;
        int ks = kbase ^ ((kc & 3) << 2);
#pragma unroll
        for (int b = 0; b < BATCH; ++b) {
            float4 h4 = *(const float4*)(&hls[(b << 10) | ks]);
            acc[b] += u4.x * h4.x + u4.y * h4.y + u4.z * h4.z + u4.w * h4.w;
        }
    }
#pragma unroll
    for (int b = 0; b < BATCH; ++b) red[kc][lc][b] = acc[b];
    __syncthreads();

    const int b2 = tid & 15, lc2 = tid >> 4;
    float z = 0.f;
#pragma unroll
    for (int k = 0; k < 16; ++k) z += red[k][lc2][b2];
    const int col2 = (lc2 >> 2) * UNITS + j0 + (lc2 & 3);
    z += xWb[((size_t)t * BATCH + b2) * GATES + col2];
    zf[lc2][b2] = z;
    __syncthreads();

    if (tid < 64) {
        const int b = tid & 15, dj = tid >> 4;
        const int j = j0 + dj;
        float zi = zf[0 * 4 + dj][b];
        float zff = zf[1 * 4 + dj][b];
        float zg = zf[2 * 4 + dj][b];
        float zo = zf[3 * 4 + dj][b];
        float c_old = cbuf[b * UNITS + j];
        float si = 1.f / (1.f + expf(-zi));
        float sf = 1.f / (1.f + expf(-zff));
        float so = 1.f / (1.f + expf(-zo));
        float c_new = sf * c_old + si * tanhf(zg);
        float h_new = so * tanhf(c_new);
        cbuf[b * UNITS + j] = c_new;
        hsx[((size_t)(t + 1) * BATCH + b) * UNITS + j] = h_new;
    }
}

// ---------- K3: projection via bf16 hi/lo 3-pass MFMA ----------
// out[m][n] = hs[m][:] @ Wc[:][n] + bc[n],  m = b*128 + t  (b = m>>7, t = m&127)
// Block: 128x128 tile, 256 threads = 4 waves (2x2), wave = 64x64, BK = 64.
// LDS: Ah/Al [128 m][64 k] bf16, Bh/Bl [128 n][64 k] bf16 (B transposed in regs
// at staging) = 64 KB. Swizzled per swz_e -> 2-way frag reads.
__global__ void __launch_bounds__(256, 2) k_proj_mfma(
    const float* __restrict__ hsx,
    const float* __restrict__ Wc,
    const float* __restrict__ bc,
    float* __restrict__ out) {
    __shared__ unsigned short Ah[128 * 64], Al[128 * 64];
    __shared__ unsigned short Bh[128 * 64], Bl[128 * 64];

    const int tid = threadIdx.x;
    // XCD-aware swizzle (4000 blocks, 4000 % 8 == 0), m-fast for Wc L2 reuse
    const int bid = blockIdx.x;
    const int swz = (bid & 7) * 500 + (bid >> 3);
    const int nt = swz / 16, mt = swz & 15;       // nt 0..249, mt = batch b
    const int n0 = nt * 128;

    // A loader coords: row ml = p*16 + (tid>>4), k4 = (tid&15)*4
    const int a_mrow = tid >> 4;
    const int a_k4   = (tid & 15) * 4;
    // B loader coords: k-run kb = (tid>>5)*8, cols nb4 = (tid&31)*4
    const int b_kb  = (tid >> 5) * 8;
    const int b_nb4 = (tid & 31) * 4;

    const int lane = tid & 63;
    const int w    = tid >> 6;
    const int wm   = (w >> 1) * 64;   // wave m-offset within tile
    const int wn   = (w & 1) * 64;    // wave n-offset
    const int lr   = lane & 15;       // frag row/col index
    const int kg   = lane >> 4;       // frag k-group (8 k's)

    f32x4 acc[4][4];
#pragma unroll
    for (int i = 0; i < 4; ++i)
#pragma unroll
        for (int j = 0; j < 4; ++j) acc[i][j] = (f32x4){0.f, 0.f, 0.f, 0.f};

    float4 rawA[8], rawB[8];
    // prologue loads (kt = 0)
#pragma unroll
    for (int p = 0; p < 8; ++p) {
        int ml = p * 16 + a_mrow;
        rawA[p] = *(const float4*)(hsx + ((size_t)(ml + 1) * BATCH + mt) * UNITS + a_k4);
    }
#pragma unroll
    for (int i = 0; i < 8; ++i)
        rawB[i] = *(const float4*)(Wc + (size_t)(b_kb + i) * VOCAB + n0 + b_nb4);

    for (int kt = 0; kt < 16; ++kt) {
        __syncthreads();   // previous tile's frag reads complete
        // ---- stage A: cvt + write (b64 runs of 4 k's) ----
#pragma unroll
        for (int p = 0; p < 8; ++p) {
            int ml = p * 16 + a_mrow;
            float v[4] = {rawA[p].x, rawA[p].y, rawA[p].z, rawA[p].w};
            ushort4 h, l;
            unsigned short* hp = (unsigned short*)&h;
            unsigned short* lp = (unsigned short*)&l;
#pragma unroll
            for (int q = 0; q < 4; ++q) {
                unsigned short hb = bf16_rne(v[q]);
                hp[q] = hb;
                lp[q] = bf16_trunc(v[q] - bf16_f32(hb));
            }
            int e = swz_e(ml, a_k4);
            *(ushort4*)(&Ah[e]) = h;
            *(ushort4*)(&Al[e]) = l;
        }
        // ---- stage B: transpose in regs, write b128 runs of 8 k's ----
#pragma unroll
        for (int nn = 0; nn < 4; ++nn) {
            unsigned short h8[8], l8[8];
#pragma unroll
            for (int i = 0; i < 8; ++i) {
                float v = ((const float*)&rawB[i])[nn];
                unsigned short hb = bf16_rne(v);
                h8[i] = hb;
                l8[i] = bf16_trunc(v - bf16_f32(hb));
            }
            int e = swz_e(b_nb4 + nn, b_kb);
            *(s16x8*)(&Bh[e]) = *(const s16x8*)h8;
            *(s16x8*)(&Bl[e]) = *(const s16x8*)l8;
        }
        __syncthreads();
        // ---- prefetch next tile's globals (overlaps MFMA below) ----
        if (kt < 15) {
            const int k0n = (kt + 1) * 64;
#pragma unroll
            for (int p = 0; p < 8; ++p) {
                int ml = p * 16 + a_mrow;
                rawA[p] = *(const float4*)(hsx + ((size_t)(ml + 1) * BATCH + mt) * UNITS + k0n + a_k4);
            }
#pragma unroll
            for (int i = 0; i < 8; ++i)
                rawB[i] = *(const float4*)(Wc + (size_t)(k0n + b_kb + i) * VOCAB + n0 + b_nb4);
        }
        // ---- MFMA: 2 k-slices x 4x4 frags x 3 passes ----
#pragma unroll
        for (int ks = 0; ks < 2; ++ks) {
            const int kofs = ks * 32 + kg * 8;
            s16x8 ah[4], al[4], bh[4], bl[4];
#pragma unroll
            for (int mi = 0; mi < 4; ++mi) {
                int e = swz_e(wm + mi * 16 + lr, kofs);
                ah[mi] = *(const s16x8*)(&Ah[e]);
                al[mi] = *(const s16x8*)(&Al[e]);
            }
#pragma unroll
            for (int ni = 0; ni < 4; ++ni) {
                int e = swz_e(wn + ni * 16 + lr, kofs);
                bh[ni] = *(const s16x8*)(&Bh[e]);
                bl[ni] = *(const s16x8*)(&Bl[e]);
            }
#pragma unroll
            for (int mi = 0; mi < 4; ++mi)
#pragma unroll
                for (int ni = 0; ni < 4; ++ni) {
                    acc[mi][ni] = __builtin_amdgcn_mfma_f32_16x16x32_bf16(ah[mi], bh[ni], acc[mi][ni], 0, 0, 0);
                    acc[mi][ni] = __builtin_amdgcn_mfma_f32_16x16x32_bf16(ah[mi], bl[ni], acc[mi][ni], 0, 0, 0);
                    acc[mi][ni] = __builtin_amdgcn_mfma_f32_16x16x32_bf16(al[mi], bh[ni], acc[mi][ni], 0, 0, 0);
                }
        }
    }

    // ---- epilogue: C/D layout col = lane&15, row = (lane>>4)*4 + reg ----
    float bcv[4];
#pragma unroll
    for (int ni = 0; ni < 4; ++ni) bcv[ni] = bc[n0 + wn + ni * 16 + lr];
#pragma unroll
    for (int mi = 0; mi < 4; ++mi) {
#pragma unroll
        for (int ni = 0; ni < 4; ++ni) {
#pragma unroll
            for (int r = 0; r < 4; ++r) {
                int grow = mt * 128 + wm + mi * 16 + kg * 4 + r;
                int gcol = n0 + wn + ni * 16 + lr;
                out[(size_t)grow * VOCAB + gcol] = acc[mi][ni][r] + bcv[ni];
            }
        }
    }
}

extern "C" void kernel_launch(void* const* d_in, const int* in_sizes, int n_in,
                              void* d_out, int out_size, void* d_ws, size_t ws_size,
                              hipStream_t stream) {
    const int*   inputs = (const int*)d_in[0];   // int32 (JAX x64 disabled)
    const float* emb  = (const float*)d_in[1];
    const float* W    = (const float*)d_in[2];
    const float* U    = (const float*)d_in[3];
    const float* bias = (const float*)d_in[4];
    const float* Wc   = (const float*)d_in[5];
    const float* bc   = (const float*)d_in[6];
    float* out = (float*)d_out;

    char* ws = (char*)d_ws;
    float* xWb  = (float*)(ws + 0);
    float* hsx  = (float*)(ws + 33554432);
    float* cbuf = (float*)(ws + 42008576);
    float* Ut   = (float*)(ws + 42074112);

    hipMemsetAsync(hsx,  0, (size_t)BATCH * UNITS * 4, stream);
    hipMemsetAsync(cbuf, 0, (size_t)BATCH * UNITS * 4, stream);

    k_transposeU<<<dim3(128, 32), 256, 0, stream>>>(U, Ut);
    k_embed_xw<<<dim3(16, 128), 256, 0, stream>>>(inputs, emb, W, bias, xWb);
    for (int t = 0; t < SEQ; ++t)
        k_lstm_step<<<256, 256, 0, stream>>>(t, Ut, xWb, hsx, cbuf);
    k_proj_mfma<<<4000, 256, 0, stream>>>(hsx, Wc, bc, out);
}

// Round 4
// 2031.531 us; speedup vs baseline: 1.5689x; 1.0145x over previous
//
#include <hip/hip_runtime.h>
#include <hip/hip_bf16.h>
#include <math.h>

// LSTM language model. Round 4: persistent-kernel recurrence with MFMA h@U
// and software grid barrier; projection unchanged.
// ws layout (~59 MB):
//   xWb   [128][16][4096] f32      33,554,432 B @ 0
//   hsx   [129][16][1024] f32       8,454,144 B @ 33,554,432  (slot 0 = h0)
//   ub_hi [256ct][32kt][64][8] bf16 8,388,608 B @ 42,008,576
//   ub_lo  (same)                   8,388,608 B @ 50,397,184
//   hb    [2][hi 16384 | lo 16384] ushort = 131,072 B @ 58,785,792
//   ctr   unsigned                  64 B @ 58,916,864

#define VOCAB 32000
#define EMBED 256
#define UNITS 1024
#define GATES 4096
#define BATCH 16
#define SEQ 128
#define NB 64   // persistent recurrence blocks

using s16x8 = __attribute__((ext_vector_type(8))) short;
using f32x4 = __attribute__((ext_vector_type(4))) float;

__device__ __forceinline__ unsigned short bf16_rne(float x) {
    unsigned u = __builtin_bit_cast(unsigned, x);
    unsigned r = u + 0x7FFFu + ((u >> 16) & 1u);
    return (unsigned short)(r >> 16);
}
__device__ __forceinline__ float bf16_f32(unsigned short h) {
    unsigned u = ((unsigned)h) << 16;
    return __builtin_bit_cast(float, u);
}
__device__ __forceinline__ unsigned short bf16_trunc(float x) {
    return (unsigned short)(__builtin_bit_cast(unsigned, x) >> 16);
}
__device__ __forceinline__ int swz_e(int r, int k) {
    return (r * 64 + k) ^ ((((r & 7) ^ ((r >> 2) & 7))) << 3);
}

// ---------- K0: U [1024][4096] -> fragment-ordered bf16 hi/lo ----------
// ub[ct][kt][lane][e]: col = ct*16 + (lane&15), k = kt*32 + (lane>>4)*8 + e
__global__ void __launch_bounds__(256) k_prep_ub(const float* __restrict__ U,
                                                 unsigned short* __restrict__ ub_hi,
                                                 unsigned short* __restrict__ ub_lo) {
    __shared__ float lds_u[1024 * 16];     // [k][16 cols], 64 KB
    const int ct = blockIdx.x;             // 0..255
    const int tid = threadIdx.x;
    for (int k = tid; k < 1024; k += 256) {
        const float4* src = (const float4*)(U + (size_t)k * GATES + ct * 16);
        float4* dst = (float4*)(&lds_u[k * 16]);
        dst[0] = src[0]; dst[1] = src[1]; dst[2] = src[2]; dst[3] = src[3];
    }
    __syncthreads();
    const int lane = tid & 63;
    const int coll = lane & 15;
    const int kg = lane >> 4;
    for (int kt = (tid >> 6); kt < 32; kt += 4) {
        const int ks = kt * 32 + kg * 8;
        unsigned short h8[8], l8[8];
#pragma unroll
        for (int e = 0; e < 8; ++e) {
            float v = lds_u[(ks + e) * 16 + coll];
            unsigned short hb = bf16_rne(v);
            h8[e] = hb;
            l8[e] = bf16_trunc(v - bf16_f32(hb));
        }
        size_t o = (((size_t)ct * 32 + kt) * 64 + lane) * 8;
        *(s16x8*)(ub_hi + o) = *(const s16x8*)h8;
        *(s16x8*)(ub_lo + o) = *(const s16x8*)l8;
    }
}

// ---------- K1: xWb[t][b][col] = emb[inputs[b][t]] @ W + bias ----------
__global__ void k_embed_xw(const int* __restrict__ inputs,
                           const float* __restrict__ emb,
                           const float* __restrict__ W,
                           const float* __restrict__ bias,
                           float* __restrict__ xWb) {
    const int t   = blockIdx.y;
    const int col = blockIdx.x * 256 + threadIdx.x;
    __shared__ float xs[BATCH][EMBED];
    __shared__ int   toks[BATCH];
    if (threadIdx.x < BATCH)
        toks[threadIdx.x] = inputs[threadIdx.x * SEQ + t];
    __syncthreads();
    for (int r = 0; r < BATCH; ++r)
        xs[r][threadIdx.x] = emb[(size_t)toks[r] * EMBED + threadIdx.x];
    __syncthreads();
    float acc[BATCH];
#pragma unroll
    for (int r = 0; r < BATCH; ++r) acc[r] = 0.f;
    for (int k = 0; k < EMBED; ++k) {
        float w = W[(size_t)k * GATES + col];
#pragma unroll
        for (int r = 0; r < BATCH; ++r) acc[r] += xs[r][k] * w;
    }
    const float bb = bias[col];
#pragma unroll
    for (int r = 0; r < BATCH; ++r)
        xWb[((size_t)t * BATCH + r) * GATES + col] = acc[r] + bb;
}

// ---------- K2: whole recurrence, persistent, software grid barrier ----------
// 64 blocks x 256 thr (4 waves). Block owns cells j0..j0+15; wave w = gate w.
// h broadcast via hb (bf16 hi/lo, A-fragment order, double-buffered):
//   elem(b, j) = (j>>5)*512 + (((j>>3)&3)*16 + b)*8 + (j&7)
__global__ void __launch_bounds__(256) k_lstm_all(
    const unsigned short* __restrict__ ub_hi,
    const unsigned short* __restrict__ ub_lo,
    const float* __restrict__ xWb,
    float* __restrict__ hsx,
    unsigned short* __restrict__ hb,
    unsigned* __restrict__ ctr) {
    __shared__ float zbuf[4 * 256];        // [gate][b*16 + jj]
    const int tid  = threadIdx.x;
    const int lane = tid & 63;
    const int w    = tid >> 6;             // gate 0..3
    const int j0   = blockIdx.x * 16;
    const int ct   = w * 64 + blockIdx.x;  // ub col-tile for this wave
    const int colw = w * UNITS + j0 + (lane & 15);
    const int bbase = (lane >> 4) * 4;

    const int b_own  = tid & 15;
    const int jj_own = tid >> 4;
    const int j_own  = j0 + jj_own;
    const int hb_e = ((j_own >> 5) * 512) + (((j_own >> 3) & 3) * 16 + b_own) * 8 + (j_own & 7);
    float c_own = 0.f;

    const unsigned short* ubh = ub_hi + (size_t)ct * 32 * 512;
    const unsigned short* ubl = ub_lo + (size_t)ct * 32 * 512;

    for (int t = 0; t < SEQ; ++t) {
        const unsigned short* hh = hb + (t & 1) * 32768;
        const unsigned short* hl = hh + 16384;
        f32x4 acc0 = {0.f, 0.f, 0.f, 0.f};
        f32x4 acc1 = {0.f, 0.f, 0.f, 0.f};
        f32x4 acc2 = {0.f, 0.f, 0.f, 0.f};
#pragma unroll 4
        for (int kt = 0; kt < 32; ++kt) {
            s16x8 ah = *(const s16x8*)(hh  + kt * 512 + lane * 8);
            s16x8 al = *(const s16x8*)(hl  + kt * 512 + lane * 8);
            s16x8 bh = *(const s16x8*)(ubh + (size_t)kt * 512 + lane * 8);
            s16x8 bl = *(const s16x8*)(ubl + (size_t)kt * 512 + lane * 8);
            acc0 = __builtin_amdgcn_mfma_f32_16x16x32_bf16(ah, bh, acc0, 0, 0, 0);
            acc1 = __builtin_amdgcn_mfma_f32_16x16x32_bf16(ah, bl, acc1, 0, 0, 0);
            acc2 = __builtin_amdgcn_mfma_f32_16x16x32_bf16(al, bh, acc2, 0, 0, 0);
        }
        // z = mfma + xWb; C/D: col = lane&15, row(b) = (lane>>4)*4 + r
        const float* xw = xWb + ((size_t)t * BATCH + bbase) * GATES + colw;
#pragma unroll
        for (int r = 0; r < 4; ++r) {
            float z = acc0[r] + acc1[r] + acc2[r] + xw[(size_t)r * GATES];
            zbuf[w * 256 + (bbase + r) * 16 + (lane & 15)] = z;
        }
        __syncthreads();
        // activation for owned cell (b_own, j_own)
        float zi = zbuf[0 * 256 + b_own * 16 + jj_own];
        float zf = zbuf[1 * 256 + b_own * 16 + jj_own];
        float zg = zbuf[2 * 256 + b_own * 16 + jj_own];
        float zo = zbuf[3 * 256 + b_own * 16 + jj_own];
        float si = 1.f / (1.f + expf(-zi));
        float sf = 1.f / (1.f + expf(-zf));
        float so = 1.f / (1.f + expf(-zo));
        float c_new = sf * c_own + si * tanhf(zg);
        float h_new = so * tanhf(c_new);
        c_own = c_new;
        hsx[((size_t)(t + 1) * BATCH + b_own) * UNITS + j_own] = h_new;
        unsigned short hhi = bf16_rne(h_new);
        unsigned short hlo = bf16_trunc(h_new - bf16_f32(hhi));
        unsigned short* nh = hb + ((t + 1) & 1) * 32768;
        nh[hb_e] = hhi;
        nh[16384 + hb_e] = hlo;
        if (t < SEQ - 1) {
            __syncthreads();   // all writes issued; zbuf reads done before reuse
            if (tid == 0) {
                __hip_atomic_fetch_add(ctr, 1u, __ATOMIC_RELEASE, __HIP_MEMORY_SCOPE_AGENT);
                const unsigned tgt = (unsigned)(t + 1) * NB;
                while (__hip_atomic_load(ctr, __ATOMIC_ACQUIRE, __HIP_MEMORY_SCOPE_AGENT) < tgt) {
                    __builtin_amdgcn_s_sleep(2);
                }
            }
            __syncthreads();
        }
    }
}

// ---------- K3: projection via bf16 hi/lo 3-pass MFMA (unchanged) ----------
__global__ void __launch_bounds__(256, 2) k_proj_mfma(
    const float* __restrict__ hsx,
    const float* __restrict__ Wc,
    const float* __restrict__ bc,
    float* __restrict__ out) {
    __shared__ unsigned short Ah[128 * 64], Al[128 * 64];
    __shared__ unsigned short Bh[128 * 64], Bl[128 * 64];

    const int tid = threadIdx.x;
    const int bid = blockIdx.x;
    const int swz = (bid & 7) * 500 + (bid >> 3);
    const int nt = swz / 16, mt = swz & 15;
    const int n0 = nt * 128;

    const int a_mrow = tid >> 4;
    const int a_k4   = (tid & 15) * 4;
    const int b_kb  = (tid >> 5) * 8;
    const int b_nb4 = (tid & 31) * 4;

    const int lane = tid & 63;
    const int w    = tid >> 6;
    const int wm   = (w >> 1) * 64;
    const int wn   = (w & 1) * 64;
    const int lr   = lane & 15;
    const int kg   = lane >> 4;

    f32x4 acc[4][4];
#pragma unroll
    for (int i = 0; i < 4; ++i)
#pragma unroll
        for (int j = 0; j < 4; ++j) acc[i][j] = (f32x4){0.f, 0.f, 0.f, 0.f};

    float4 rawA[8], rawB[8];
#pragma unroll
    for (int p = 0; p < 8; ++p) {
        int ml = p * 16 + a_mrow;
        rawA[p] = *(const float4*)(hsx + ((size_t)(ml + 1) * BATCH + mt) * UNITS + a_k4);
    }
#pragma unroll
    for (int i = 0; i < 8; ++i)
        rawB[i] = *(const float4*)(Wc + (size_t)(b_kb + i) * VOCAB + n0 + b_nb4);

    for (int kt = 0; kt < 16; ++kt) {
        __syncthreads();
#pragma unroll
        for (int p = 0; p < 8; ++p) {
            int ml = p * 16 + a_mrow;
            float v[4] = {rawA[p].x, rawA[p].y, rawA[p].z, rawA[p].w};
            ushort4 h, l;
            unsigned short* hp = (unsigned short*)&h;
            unsigned short* lp = (unsigned short*)&l;
#pragma unroll
            for (int q = 0; q < 4; ++q) {
                unsigned short hb = bf16_rne(v[q]);
                hp[q] = hb;
                lp[q] = bf16_trunc(v[q] - bf16_f32(hb));
            }
            int e = swz_e(ml, a_k4);
            *(ushort4*)(&Ah[e]) = h;
            *(ushort4*)(&Al[e]) = l;
        }
#pragma unroll
        for (int nn = 0; nn < 4; ++nn) {
            unsigned short h8[8], l8[8];
#pragma unroll
            for (int i = 0; i < 8; ++i) {
                float v = ((const float*)&rawB[i])[nn];
                unsigned short hb = bf16_rne(v);
                h8[i] = hb;
                l8[i] = bf16_trunc(v - bf16_f32(hb));
            }
            int e = swz_e(b_nb4 + nn, b_kb);
            *(s16x8*)(&Bh[e]) = *(const s16x8*)h8;
            *(s16x8*)(&Bl[e]) = *(const s16x8*)l8;
        }
        __syncthreads();
        if (kt < 15) {
            const int k0n = (kt + 1) * 64;
#pragma unroll
            for (int p = 0; p < 8; ++p) {
                int ml = p * 16 + a_mrow;
                rawA[p] = *(const float4*)(hsx + ((size_t)(ml + 1) * BATCH + mt) * UNITS + k0n + a_k4);
            }
#pragma unroll
            for (int i = 0; i < 8; ++i)
                rawB[i] = *(const float4*)(Wc + (size_t)(k0n + b_kb + i) * VOCAB + n0 + b_nb4);
        }
#pragma unroll
        for (int ks = 0; ks < 2; ++ks) {
            const int kofs = ks * 32 + kg * 8;
            s16x8 ah[4], al[4], bh[4], bl[4];
#pragma unroll
            for (int mi = 0; mi < 4; ++mi) {
                int e = swz_e(wm + mi * 16 + lr, kofs);
                ah[mi] = *(const s16x8*)(&Ah[e]);
                al[mi] = *(const s16x8*)(&Al[e]);
            }
#pragma unroll
            for (int ni = 0; ni < 4; ++ni) {
                int e = swz_e(wn + ni * 16 + lr, kofs);
                bh[ni] = *(const s16x8*)(&Bh[e]);
                bl[ni] = *(const s16x8*)(&Bl[e]);
            }
#pragma unroll
            for (int mi = 0; mi < 4; ++mi)
#pragma unroll
                for (int ni = 0; ni < 4; ++ni) {
                    acc[mi][ni] = __builtin_amdgcn_mfma_f32_16x16x32_bf16(ah[mi], bh[ni], acc[mi][ni], 0, 0, 0);
                    acc[mi][ni] = __builtin_amdgcn_mfma_f32_16x16x32_bf16(ah[mi], bl[ni], acc[mi][ni], 0, 0, 0);
                    acc[mi][ni] = __builtin_amdgcn_mfma_f32_16x16x32_bf16(al[mi], bh[ni], acc[mi][ni], 0, 0, 0);
                }
        }
    }

    float bcv[4];
#pragma unroll
    for (int ni = 0; ni < 4; ++ni) bcv[ni] = bc[n0 + wn + ni * 16 + lr];
#pragma unroll
    for (int mi = 0; mi < 4; ++mi) {
#pragma unroll
        for (int ni = 0; ni < 4; ++ni) {
#pragma unroll
            for (int r = 0; r < 4; ++r) {
                int grow = mt * 128 + wm + mi * 16 + kg * 4 + r;
                int gcol = n0 + wn + ni * 16 + lr;
                out[(size_t)grow * VOCAB + gcol] = acc[mi][ni][r] + bcv[ni];
            }
        }
    }
}

extern "C" void kernel_launch(void* const* d_in, const int* in_sizes, int n_in,
                              void* d_out, int out_size, void* d_ws, size_t ws_size,
                              hipStream_t stream) {
    const int*   inputs = (const int*)d_in[0];   // int32 (JAX x64 disabled)
    const float* emb  = (const float*)d_in[1];
    const float* W    = (const float*)d_in[2];
    const float* U    = (const float*)d_in[3];
    const float* bias = (const float*)d_in[4];
    const float* Wc   = (const float*)d_in[5];
    const float* bc   = (const float*)d_in[6];
    float* out = (float*)d_out;

    char* ws = (char*)d_ws;
    float*          xWb   = (float*)(ws + 0);
    float*          hsx   = (float*)(ws + 33554432);
    unsigned short* ub_hi = (unsigned short*)(ws + 42008576);
    unsigned short* ub_lo = (unsigned short*)(ws + 50397184);
    unsigned short* hb    = (unsigned short*)(ws + 58785792);
    unsigned*       ctr   = (unsigned*)(ws + 58916864);

    // h0 = 0 (f32 + bf16 buffers), barrier counter = 0 — every call
    hipMemsetAsync(hsx, 0, (size_t)BATCH * UNITS * 4, stream);
    hipMemsetAsync(hb,  0, 65536, stream);
    hipMemsetAsync(ctr, 0, 64, stream);

    k_prep_ub<<<256, 256, 0, stream>>>(U, ub_hi, ub_lo);
    k_embed_xw<<<dim3(16, 128), 256, 0, stream>>>(inputs, emb, W, bias, xWb);
    k_lstm_all<<<NB, 256, 0, stream>>>(ub_hi, ub_lo, xWb, hsx, hb, ctr);
    k_proj_mfma<<<4000, 256, 0, stream>>>(hsx, Wc, bc, out);
}

// Round 5
// 1835.805 us; speedup vs baseline: 1.7362x; 1.1066x over previous
//
#include <hip/hip_runtime.h>
#include <hip/hip_bf16.h>
#include <math.h>

// LSTM language model. Round 5: persistent recurrence with U held in VGPRs
// (loaded once), K-split waves, and a lane-parallel flag-array grid barrier.
// ws layout (~59 MB):
//   xWb   [128][16][4096] f32      33,554,432 B @ 0
//   hsx   [129][16][1024] f32       8,454,144 B @ 33,554,432  (slot 0 = h0)
//   ub_hi [256ct][32kt][64][8] bf16 8,388,608 B @ 42,008,576
//   ub_lo  (same)                   8,388,608 B @ 50,397,184
//   hb    [2][hi 16384 | lo 16384] ushort = 131,072 B @ 58,785,792
//   flags [64][16] unsigned (64B-padded slots) = 4096 B @ 58,916,864

#define VOCAB 32000
#define EMBED 256
#define UNITS 1024
#define GATES 4096
#define BATCH 16
#define SEQ 128
#define NB 64   // persistent recurrence blocks

using s16x8 = __attribute__((ext_vector_type(8))) short;
using f32x4 = __attribute__((ext_vector_type(4))) float;

__device__ __forceinline__ unsigned short bf16_rne(float x) {
    unsigned u = __builtin_bit_cast(unsigned, x);
    unsigned r = u + 0x7FFFu + ((u >> 16) & 1u);
    return (unsigned short)(r >> 16);
}
__device__ __forceinline__ float bf16_f32(unsigned short h) {
    unsigned u = ((unsigned)h) << 16;
    return __builtin_bit_cast(float, u);
}
__device__ __forceinline__ unsigned short bf16_trunc(float x) {
    return (unsigned short)(__builtin_bit_cast(unsigned, x) >> 16);
}
__device__ __forceinline__ int swz_e(int r, int k) {
    return (r * 64 + k) ^ ((((r & 7) ^ ((r >> 2) & 7))) << 3);
}

// ---------- K0: U [1024][4096] -> fragment-ordered bf16 hi/lo ----------
// ub[ct][kt][lane][e]: col = ct*16 + (lane&15), k = kt*32 + (lane>>4)*8 + e
__global__ void __launch_bounds__(256) k_prep_ub(const float* __restrict__ U,
                                                 unsigned short* __restrict__ ub_hi,
                                                 unsigned short* __restrict__ ub_lo) {
    __shared__ float lds_u[1024 * 16];     // [k][16 cols], 64 KB
    const int ct = blockIdx.x;             // 0..255
    const int tid = threadIdx.x;
    for (int k = tid; k < 1024; k += 256) {
        const float4* src = (const float4*)(U + (size_t)k * GATES + ct * 16);
        float4* dst = (float4*)(&lds_u[k * 16]);
        dst[0] = src[0]; dst[1] = src[1]; dst[2] = src[2]; dst[3] = src[3];
    }
    __syncthreads();
    const int lane = tid & 63;
    const int coll = lane & 15;
    const int kg = lane >> 4;
    for (int kt = (tid >> 6); kt < 32; kt += 4) {
        const int ks = kt * 32 + kg * 8;
        unsigned short h8[8], l8[8];
#pragma unroll
        for (int e = 0; e < 8; ++e) {
            float v = lds_u[(ks + e) * 16 + coll];
            unsigned short hb = bf16_rne(v);
            h8[e] = hb;
            l8[e] = bf16_trunc(v - bf16_f32(hb));
        }
        size_t o = (((size_t)ct * 32 + kt) * 64 + lane) * 8;
        *(s16x8*)(ub_hi + o) = *(const s16x8*)h8;
        *(s16x8*)(ub_lo + o) = *(const s16x8*)l8;
    }
}

// ---------- K1: xWb[t][b][col] = emb[inputs[b][t]] @ W + bias ----------
__global__ void k_embed_xw(const int* __restrict__ inputs,
                           const float* __restrict__ emb,
                           const float* __restrict__ W,
                           const float* __restrict__ bias,
                           float* __restrict__ xWb) {
    const int t   = blockIdx.y;
    const int col = blockIdx.x * 256 + threadIdx.x;
    __shared__ float xs[BATCH][EMBED];
    __shared__ int   toks[BATCH];
    if (threadIdx.x < BATCH)
        toks[threadIdx.x] = inputs[threadIdx.x * SEQ + t];
    __syncthreads();
    for (int r = 0; r < BATCH; ++r)
        xs[r][threadIdx.x] = emb[(size_t)toks[r] * EMBED + threadIdx.x];
    __syncthreads();
    float acc[BATCH];
#pragma unroll
    for (int r = 0; r < BATCH; ++r) acc[r] = 0.f;
    for (int k = 0; k < EMBED; ++k) {
        float w = W[(size_t)k * GATES + col];
#pragma unroll
        for (int r = 0; r < BATCH; ++r) acc[r] += xs[r][k] * w;
    }
    const float bb = bias[col];
#pragma unroll
    for (int r = 0; r < BATCH; ++r)
        xWb[((size_t)t * BATCH + r) * GATES + col] = acc[r] + bb;
}

// ---------- K2: whole recurrence, persistent ----------
// 64 blocks x 256 thr (4 waves). Block owns cells j0..j0+15 across all 4
// gates; wave w covers k in [256w, 256w+256) for all 4 gate col-tiles.
// U frags live in VGPRs for the whole kernel (loaded once).
// h broadcast via hb (bf16 hi/lo, A-fragment order, double-buffered):
//   elem(b, j) = (j>>5)*512 + (((j>>3)&3)*16 + b)*8 + (j&7)
// Grid barrier: flags[bid] = epoch, release store; wave 0 polls all 64
// flags lane-parallel with acquire loads.
__global__ void __launch_bounds__(256, 1) k_lstm_all(
    const unsigned short* __restrict__ ub_hi,
    const unsigned short* __restrict__ ub_lo,
    const float* __restrict__ xWb,
    float* __restrict__ hsx,
    unsigned short* __restrict__ hb,
    unsigned* __restrict__ flags) {
    __shared__ float zpart[4][4][256];     // [wave][gate][b*16+jj], 16 KB
    const int tid  = threadIdx.x;
    const int lane = tid & 63;
    const int w    = tid >> 6;             // k-slice 0..3
    const int bid  = blockIdx.x;
    const int j0   = bid * 16;

    const int b_own  = tid >> 4;           // batch row owned (reduce phase)
    const int jj_own = tid & 15;           // local cell owned
    const int j_own  = j0 + jj_own;
    const int hb_e = ((j_own >> 5) * 512) + (((j_own >> 3) & 3) * 16 + b_own) * 8 + (j_own & 7);
    float c_own = 0.f;

    // ---- preload U fragments into registers (once) ----
    s16x8 Uh[4][8], Ul[4][8];
#pragma unroll
    for (int g = 0; g < 4; ++g)
#pragma unroll
        for (int q = 0; q < 8; ++q) {
            size_t o = (((size_t)(g * 64 + bid) * 32) + (w * 8 + q)) * 512 + lane * 8;
            Uh[g][q] = *(const s16x8*)(ub_hi + o);
            Ul[g][q] = *(const s16x8*)(ub_lo + o);
        }

    for (int t = 0; t < SEQ; ++t) {
        // xW gather for owned cells (independent of h -> issues early)
        const float* xwp = xWb + ((size_t)t * BATCH + b_own) * GATES + j_own;
        float xw0 = xwp[0], xw1 = xwp[UNITS], xw2 = xwp[2 * UNITS], xw3 = xwp[3 * UNITS];

        // h fragments for this wave's k-slice
        const unsigned short* hh = hb + (t & 1) * 32768;
        const unsigned short* hl = hh + 16384;
        s16x8 Hh[8], Hl[8];
#pragma unroll
        for (int q = 0; q < 8; ++q) {
            const int kt = w * 8 + q;
            Hh[q] = *(const s16x8*)(hh + kt * 512 + lane * 8);
            Hl[q] = *(const s16x8*)(hl + kt * 512 + lane * 8);
        }

        f32x4 a0[4], a1[4], a2[4];
#pragma unroll
        for (int g = 0; g < 4; ++g) {
            a0[g] = (f32x4){0.f, 0.f, 0.f, 0.f};
            a1[g] = (f32x4){0.f, 0.f, 0.f, 0.f};
            a2[g] = (f32x4){0.f, 0.f, 0.f, 0.f};
        }
#pragma unroll
        for (int q = 0; q < 8; ++q)
#pragma unroll
            for (int g = 0; g < 4; ++g) {
                a0[g] = __builtin_amdgcn_mfma_f32_16x16x32_bf16(Hh[q], Uh[g][q], a0[g], 0, 0, 0);
                a1[g] = __builtin_amdgcn_mfma_f32_16x16x32_bf16(Hh[q], Ul[g][q], a1[g], 0, 0, 0);
                a2[g] = __builtin_amdgcn_mfma_f32_16x16x32_bf16(Hl[q], Uh[g][q], a2[g], 0, 0, 0);
            }

        __syncthreads();   // previous step's zpart reads complete
#pragma unroll
        for (int g = 0; g < 4; ++g)
#pragma unroll
            for (int r = 0; r < 4; ++r)
                zpart[w][g][((lane >> 4) * 4 + r) * 16 + (lane & 15)] =
                    a0[g][r] + a1[g][r] + a2[g][r];
        __syncthreads();

        // reduce across waves + activations for owned cell (b_own, j_own)
        const int zi_idx = b_own * 16 + jj_own;
        float zi = xw0, zf = xw1, zg = xw2, zo = xw3;
#pragma unroll
        for (int ww = 0; ww < 4; ++ww) {
            zi += zpart[ww][0][zi_idx];
            zf += zpart[ww][1][zi_idx];
            zg += zpart[ww][2][zi_idx];
            zo += zpart[ww][3][zi_idx];
        }
        float si = 1.f / (1.f + expf(-zi));
        float sf = 1.f / (1.f + expf(-zf));
        float so = 1.f / (1.f + expf(-zo));
        float c_new = sf * c_own + si * tanhf(zg);
        float h_new = so * tanhf(c_new);
        c_own = c_new;
        hsx[((size_t)(t + 1) * BATCH + b_own) * UNITS + j_own] = h_new;
        unsigned short hhi = bf16_rne(h_new);
        unsigned short hlo = bf16_trunc(h_new - bf16_f32(hhi));
        unsigned short* nh = hb + ((t + 1) & 1) * 32768;
        nh[hb_e] = hhi;
        nh[16384 + hb_e] = hlo;

        if (t < SEQ - 1) {
            __syncthreads();   // all h writes issued (vmcnt drained by barrier)
            if (tid == 0) {
                __threadfence();
                __hip_atomic_store(&flags[bid * 16], (unsigned)(t + 1),
                                   __ATOMIC_RELEASE, __HIP_MEMORY_SCOPE_AGENT);
            }
            if (tid < 64) {
                const unsigned tgt = (unsigned)(t + 1);
                while (true) {
                    unsigned v = __hip_atomic_load(&flags[tid * 16],
                                                   __ATOMIC_ACQUIRE, __HIP_MEMORY_SCOPE_AGENT);
                    if (__all(v >= tgt)) break;
                    __builtin_amdgcn_s_sleep(1);
                }
            }
            __syncthreads();
        }
    }
}

// ---------- K3: projection via bf16 hi/lo 3-pass MFMA (unchanged) ----------
__global__ void __launch_bounds__(256, 2) k_proj_mfma(
    const float* __restrict__ hsx,
    const float* __restrict__ Wc,
    const float* __restrict__ bc,
    float* __restrict__ out) {
    __shared__ unsigned short Ah[128 * 64], Al[128 * 64];
    __shared__ unsigned short Bh[128 * 64], Bl[128 * 64];

    const int tid = threadIdx.x;
    const int bid = blockIdx.x;
    const int swz = (bid & 7) * 500 + (bid >> 3);
    const int nt = swz / 16, mt = swz & 15;
    const int n0 = nt * 128;

    const int a_mrow = tid >> 4;
    const int a_k4   = (tid & 15) * 4;
    const int b_kb  = (tid >> 5) * 8;
    const int b_nb4 = (tid & 31) * 4;

    const int lane = tid & 63;
    const int w    = tid >> 6;
    const int wm   = (w >> 1) * 64;
    const int wn   = (w & 1) * 64;
    const int lr   = lane & 15;
    const int kg   = lane >> 4;

    f32x4 acc[4][4];
#pragma unroll
    for (int i = 0; i < 4; ++i)
#pragma unroll
        for (int j = 0; j < 4; ++j) acc[i][j] = (f32x4){0.f, 0.f, 0.f, 0.f};

    float4 rawA[8], rawB[8];
#pragma unroll
    for (int p = 0; p < 8; ++p) {
        int ml = p * 16 + a_mrow;
        rawA[p] = *(const float4*)(hsx + ((size_t)(ml + 1) * BATCH + mt) * UNITS + a_k4);
    }
#pragma unroll
    for (int i = 0; i < 8; ++i)
        rawB[i] = *(const float4*)(Wc + (size_t)(b_kb + i) * VOCAB + n0 + b_nb4);

    for (int kt = 0; kt < 16; ++kt) {
        __syncthreads();
#pragma unroll
        for (int p = 0; p < 8; ++p) {
            int ml = p * 16 + a_mrow;
            float v[4] = {rawA[p].x, rawA[p].y, rawA[p].z, rawA[p].w};
            ushort4 h, l;
            unsigned short* hp = (unsigned short*)&h;
            unsigned short* lp = (unsigned short*)&l;
#pragma unroll
            for (int q = 0; q < 4; ++q) {
                unsigned short hb = bf16_rne(v[q]);
                hp[q] = hb;
                lp[q] = bf16_trunc(v[q] - bf16_f32(hb));
            }
            int e = swz_e(ml, a_k4);
            *(ushort4*)(&Ah[e]) = h;
            *(ushort4*)(&Al[e]) = l;
        }
#pragma unroll
        for (int nn = 0; nn < 4; ++nn) {
            unsigned short h8[8], l8[8];
#pragma unroll
            for (int i = 0; i < 8; ++i) {
                float v = ((const float*)&rawB[i])[nn];
                unsigned short hb = bf16_rne(v);
                h8[i] = hb;
                l8[i] = bf16_trunc(v - bf16_f32(hb));
            }
            int e = swz_e(b_nb4 + nn, b_kb);
            *(s16x8*)(&Bh[e]) = *(const s16x8*)h8;
            *(s16x8*)(&Bl[e]) = *(const s16x8*)l8;
        }
        __syncthreads();
        if (kt < 15) {
            const int k0n = (kt + 1) * 64;
#pragma unroll
            for (int p = 0; p < 8; ++p) {
                int ml = p * 16 + a_mrow;
                rawA[p] = *(const float4*)(hsx + ((size_t)(ml + 1) * BATCH + mt) * UNITS + k0n + a_k4);
            }
#pragma unroll
            for (int i = 0; i < 8; ++i)
                rawB[i] = *(const float4*)(Wc + (size_t)(k0n + b_kb + i) * VOCAB + n0 + b_nb4);
        }
#pragma unroll
        for (int ks = 0; ks < 2; ++ks) {
            const int kofs = ks * 32 + kg * 8;
            s16x8 ah[4], al[4], bh[4], bl[4];
#pragma unroll
            for (int mi = 0; mi < 4; ++mi) {
                int e = swz_e(wm + mi * 16 + lr, kofs);
                ah[mi] = *(const s16x8*)(&Ah[e]);
                al[mi] = *(const s16x8*)(&Al[e]);
            }
#pragma unroll
            for (int ni = 0; ni < 4; ++ni) {
                int e = swz_e(wn + ni * 16 + lr, kofs);
                bh[ni] = *(const s16x8*)(&Bh[e]);
                bl[ni] = *(const s16x8*)(&Bl[e]);
            }
#pragma unroll
            for (int mi = 0; mi < 4; ++mi)
#pragma unroll
                for (int ni = 0; ni < 4; ++ni) {
                    acc[mi][ni] = __builtin_amdgcn_mfma_f32_16x16x32_bf16(ah[mi], bh[ni], acc[mi][ni], 0, 0, 0);
                    acc[mi][ni] = __builtin_amdgcn_mfma_f32_16x16x32_bf16(ah[mi], bl[ni], acc[mi][ni], 0, 0, 0);
                    acc[mi][ni] = __builtin_amdgcn_mfma_f32_16x16x32_bf16(al[mi], bh[ni], acc[mi][ni], 0, 0, 0);
                }
        }
    }

    float bcv[4];
#pragma unroll
    for (int ni = 0; ni < 4; ++ni) bcv[ni] = bc[n0 + wn + ni * 16 + lr];
#pragma unroll
    for (int mi = 0; mi < 4; ++mi) {
#pragma unroll
        for (int ni = 0; ni < 4; ++ni) {
#pragma unroll
            for (int r = 0; r < 4; ++r) {
                int grow = mt * 128 + wm + mi * 16 + kg * 4 + r;
                int gcol = n0 + wn + ni * 16 + lr;
                out[(size_t)grow * VOCAB + gcol] = acc[mi][ni][r] + bcv[ni];
            }
        }
    }
}

extern "C" void kernel_launch(void* const* d_in, const int* in_sizes, int n_in,
                              void* d_out, int out_size, void* d_ws, size_t ws_size,
                              hipStream_t stream) {
    const int*   inputs = (const int*)d_in[0];   // int32 (JAX x64 disabled)
    const float* emb  = (const float*)d_in[1];
    const float* W    = (const float*)d_in[2];
    const float* U    = (const float*)d_in[3];
    const float* bias = (const float*)d_in[4];
    const float* Wc   = (const float*)d_in[5];
    const float* bc   = (const float*)d_in[6];
    float* out = (float*)d_out;

    char* ws = (char*)d_ws;
    float*          xWb   = (float*)(ws + 0);
    float*          hsx   = (float*)(ws + 33554432);
    unsigned short* ub_hi = (unsigned short*)(ws + 42008576);
    unsigned short* ub_lo = (unsigned short*)(ws + 50397184);
    unsigned short* hb    = (unsigned short*)(ws + 58785792);
    unsigned*       flags = (unsigned*)(ws + 58916864);

    // h0 = 0 (f32 + bf16 buffers), barrier flags = 0 — every call
    hipMemsetAsync(hsx, 0, (size_t)BATCH * UNITS * 4, stream);
    hipMemsetAsync(hb,  0, 65536, stream);
    hipMemsetAsync(flags, 0, 4096, stream);

    k_prep_ub<<<256, 256, 0, stream>>>(U, ub_hi, ub_lo);
    k_embed_xw<<<dim3(16, 128), 256, 0, stream>>>(inputs, emb, W, bias, xWb);
    k_lstm_all<<<NB, 256, 0, stream>>>(ub_hi, ub_lo, xWb, hsx, hb, flags);
    k_proj_mfma<<<4000, 256, 0, stream>>>(hsx, Wc, bc, out);
}

// Round 6
// 1260.276 us; speedup vs baseline: 2.5290x; 1.4567x over previous
//
#include <hip/hip_runtime.h>
#include <hip/hip_bf16.h>
#include <math.h>

// LSTM language model. Round 6: recurrence barrier/broadcast moved to RELAXED
// agent-scope atomics (sc1, no L2 writeback/invalidate) with hand-rolled
// ordering. Projection unchanged.
// ws layout (~59 MB):
//   xWb   [128][16][4096] f32      33,554,432 B @ 0
//   hsx   [129][16][1024] f32       8,454,144 B @ 33,554,432  (slot 0 = h0)
//   ub_hi [256ct][32kt][64][8] bf16 8,388,608 B @ 42,008,576
//   ub_lo  (same)                   8,388,608 B @ 50,397,184
//   hb    [2][hi 16384 | lo 16384] ushort = 131,072 B @ 58,785,792
//   flags [64][16] unsigned (64B-padded slots) = 4096 B @ 58,916,864

#define VOCAB 32000
#define EMBED 256
#define UNITS 1024
#define GATES 4096
#define BATCH 16
#define SEQ 128
#define NB 64   // persistent recurrence blocks

using s16x8 = __attribute__((ext_vector_type(8))) short;
using f32x4 = __attribute__((ext_vector_type(4))) float;

__device__ __forceinline__ unsigned short bf16_rne(float x) {
    unsigned u = __builtin_bit_cast(unsigned, x);
    unsigned r = u + 0x7FFFu + ((u >> 16) & 1u);
    return (unsigned short)(r >> 16);
}
__device__ __forceinline__ float bf16_f32(unsigned short h) {
    unsigned u = ((unsigned)h) << 16;
    return __builtin_bit_cast(float, u);
}
__device__ __forceinline__ unsigned short bf16_trunc(float x) {
    return (unsigned short)(__builtin_bit_cast(unsigned, x) >> 16);
}
__device__ __forceinline__ int swz_e(int r, int k) {
    return (r * 64 + k) ^ ((((r & 7) ^ ((r >> 2) & 7))) << 3);
}
// 16B fragment load via two relaxed agent-scope (sc1) u64 loads: performed at
// the device coherence point; never served by (possibly stale) per-XCD L2.
__device__ __forceinline__ s16x8 load_frag_coherent(const unsigned short* p) {
    union { unsigned long long q[2]; s16x8 v; } u;
    u.q[0] = __hip_atomic_load((const unsigned long long*)p,
                               __ATOMIC_RELAXED, __HIP_MEMORY_SCOPE_AGENT);
    u.q[1] = __hip_atomic_load((const unsigned long long*)(p + 4),
                               __ATOMIC_RELAXED, __HIP_MEMORY_SCOPE_AGENT);
    return u.v;
}

// ---------- K0: U [1024][4096] -> fragment-ordered bf16 hi/lo ----------
// ub[ct][kt][lane][e]: col = ct*16 + (lane&15), k = kt*32 + (lane>>4)*8 + e
__global__ void __launch_bounds__(256) k_prep_ub(const float* __restrict__ U,
                                                 unsigned short* __restrict__ ub_hi,
                                                 unsigned short* __restrict__ ub_lo) {
    __shared__ float lds_u[1024 * 16];     // [k][16 cols], 64 KB
    const int ct = blockIdx.x;             // 0..255
    const int tid = threadIdx.x;
    for (int k = tid; k < 1024; k += 256) {
        const float4* src = (const float4*)(U + (size_t)k * GATES + ct * 16);
        float4* dst = (float4*)(&lds_u[k * 16]);
        dst[0] = src[0]; dst[1] = src[1]; dst[2] = src[2]; dst[3] = src[3];
    }
    __syncthreads();
    const int lane = tid & 63;
    const int coll = lane & 15;
    const int kg = lane >> 4;
    for (int kt = (tid >> 6); kt < 32; kt += 4) {
        const int ks = kt * 32 + kg * 8;
        unsigned short h8[8], l8[8];
#pragma unroll
        for (int e = 0; e < 8; ++e) {
            float v = lds_u[(ks + e) * 16 + coll];
            unsigned short hb = bf16_rne(v);
            h8[e] = hb;
            l8[e] = bf16_trunc(v - bf16_f32(hb));
        }
        size_t o = (((size_t)ct * 32 + kt) * 64 + lane) * 8;
        *(s16x8*)(ub_hi + o) = *(const s16x8*)h8;
        *(s16x8*)(ub_lo + o) = *(const s16x8*)l8;
    }
}

// ---------- K1: xWb[t][b][col] = emb[inputs[b][t]] @ W + bias ----------
__global__ void k_embed_xw(const int* __restrict__ inputs,
                           const float* __restrict__ emb,
                           const float* __restrict__ W,
                           const float* __restrict__ bias,
                           float* __restrict__ xWb) {
    const int t   = blockIdx.y;
    const int col = blockIdx.x * 256 + threadIdx.x;
    __shared__ float xs[BATCH][EMBED];
    __shared__ int   toks[BATCH];
    if (threadIdx.x < BATCH)
        toks[threadIdx.x] = inputs[threadIdx.x * SEQ + t];
    __syncthreads();
    for (int r = 0; r < BATCH; ++r)
        xs[r][threadIdx.x] = emb[(size_t)toks[r] * EMBED + threadIdx.x];
    __syncthreads();
    float acc[BATCH];
#pragma unroll
    for (int r = 0; r < BATCH; ++r) acc[r] = 0.f;
    for (int k = 0; k < EMBED; ++k) {
        float w = W[(size_t)k * GATES + col];
#pragma unroll
        for (int r = 0; r < BATCH; ++r) acc[r] += xs[r][k] * w;
    }
    const float bb = bias[col];
#pragma unroll
    for (int r = 0; r < BATCH; ++r)
        xWb[((size_t)t * BATCH + r) * GATES + col] = acc[r] + bb;
}

// ---------- K2: whole recurrence, persistent ----------
// 64 blocks x 256 thr (4 waves). Block owns cells j0..j0+15 across all 4
// gates; wave w covers k in [256w, 256w+256) for all 4 gate col-tiles.
// h broadcast via hb (bf16 hi/lo, A-fragment order, double-buffered):
//   elem(b, j) = (j>>5)*512 + (((j>>3)&3)*16 + b)*8 + (j&7)
// All cross-block traffic (hb, flags) uses RELAXED agent-scope atomics (sc1):
// no buffer_wbl2 / buffer_inv on the critical path. Ordering:
//   h stores (sc1) -> s_waitcnt vmcnt(0) -> syncthreads -> flag store (sc1)
//   -> relaxed poll -> sched_barrier -> h loads (sc1 u64).
__global__ void __launch_bounds__(256, 1) k_lstm_all(
    const unsigned short* __restrict__ ub_hi,
    const unsigned short* __restrict__ ub_lo,
    const float* __restrict__ xWb,
    float* __restrict__ hsx,
    unsigned short* __restrict__ hb,
    unsigned* __restrict__ flags) {
    __shared__ float zpart[4][4][256];     // [wave][gate][b*16+jj], 16 KB
    const int tid  = threadIdx.x;
    const int lane = tid & 63;
    const int w    = tid >> 6;             // k-slice 0..3
    const int bid  = blockIdx.x;
    const int j0   = bid * 16;

    const int b_own  = tid >> 4;           // batch row owned (reduce phase)
    const int jj_own = tid & 15;           // local cell owned
    const int j_own  = j0 + jj_own;
    const int hb_e = ((j_own >> 5) * 512) + (((j_own >> 3) & 3) * 16 + b_own) * 8 + (j_own & 7);
    float c_own = 0.f;

    // ---- preload U fragments (L2-resident after first step) ----
    s16x8 Uh[4][8], Ul[4][8];
#pragma unroll
    for (int g = 0; g < 4; ++g)
#pragma unroll
        for (int q = 0; q < 8; ++q) {
            size_t o = (((size_t)(g * 64 + bid) * 32) + (w * 8 + q)) * 512 + lane * 8;
            Uh[g][q] = *(const s16x8*)(ub_hi + o);
            Ul[g][q] = *(const s16x8*)(ub_lo + o);
        }

    for (int t = 0; t < SEQ; ++t) {
        // xW gather for owned cells (independent of h -> issues early)
        const float* xwp = xWb + ((size_t)t * BATCH + b_own) * GATES + j_own;
        float xw0 = xwp[0], xw1 = xwp[UNITS], xw2 = xwp[2 * UNITS], xw3 = xwp[3 * UNITS];

        // h fragments for this wave's k-slice (coherent sc1 loads)
        const unsigned short* hh = hb + (t & 1) * 32768;
        const unsigned short* hl = hh + 16384;
        s16x8 Hh[8], Hl[8];
#pragma unroll
        for (int q = 0; q < 8; ++q) {
            const int kt = w * 8 + q;
            Hh[q] = load_frag_coherent(hh + kt * 512 + lane * 8);
            Hl[q] = load_frag_coherent(hl + kt * 512 + lane * 8);
        }

        f32x4 a0[4], a1[4], a2[4];
#pragma unroll
        for (int g = 0; g < 4; ++g) {
            a0[g] = (f32x4){0.f, 0.f, 0.f, 0.f};
            a1[g] = (f32x4){0.f, 0.f, 0.f, 0.f};
            a2[g] = (f32x4){0.f, 0.f, 0.f, 0.f};
        }
#pragma unroll
        for (int q = 0; q < 8; ++q)
#pragma unroll
            for (int g = 0; g < 4; ++g) {
                a0[g] = __builtin_amdgcn_mfma_f32_16x16x32_bf16(Hh[q], Uh[g][q], a0[g], 0, 0, 0);
                a1[g] = __builtin_amdgcn_mfma_f32_16x16x32_bf16(Hh[q], Ul[g][q], a1[g], 0, 0, 0);
                a2[g] = __builtin_amdgcn_mfma_f32_16x16x32_bf16(Hl[q], Uh[g][q], a2[g], 0, 0, 0);
            }

        __syncthreads();   // previous step's zpart reads complete
#pragma unroll
        for (int g = 0; g < 4; ++g)
#pragma unroll
            for (int r = 0; r < 4; ++r)
                zpart[w][g][((lane >> 4) * 4 + r) * 16 + (lane & 15)] =
                    a0[g][r] + a1[g][r] + a2[g][r];
        __syncthreads();

        // reduce across waves + activations for owned cell (b_own, j_own)
        const int zi_idx = b_own * 16 + jj_own;
        float zi = xw0, zf = xw1, zg = xw2, zo = xw3;
#pragma unroll
        for (int ww = 0; ww < 4; ++ww) {
            zi += zpart[ww][0][zi_idx];
            zf += zpart[ww][1][zi_idx];
            zg += zpart[ww][2][zi_idx];
            zo += zpart[ww][3][zi_idx];
        }
        float si = 1.f / (1.f + expf(-zi));
        float sf = 1.f / (1.f + expf(-zf));
        float so = 1.f / (1.f + expf(-zo));
        float c_new = sf * c_own + si * tanhf(zg);
        float h_new = so * tanhf(c_new);
        c_own = c_new;
        hsx[((size_t)(t + 1) * BATCH + b_own) * UNITS + j_own] = h_new;

        // pack lane-pairs (jj even/odd share adjacent hb elements) -> u32
        // relaxed agent (sc1) stores, no cache maintenance
        int hhi = (int)bf16_rne(h_new);
        int hlo = (int)bf16_trunc(h_new - bf16_f32((unsigned short)hhi));
        int hhi_nb = __shfl_xor(hhi, 1);
        int hlo_nb = __shfl_xor(hlo, 1);
        unsigned short* nh = hb + ((t + 1) & 1) * 32768;
        if ((tid & 1) == 0) {
            unsigned hp = (unsigned)(unsigned short)hhi | ((unsigned)(unsigned short)hhi_nb << 16);
            unsigned lp = (unsigned)(unsigned short)hlo | ((unsigned)(unsigned short)hlo_nb << 16);
            __hip_atomic_store((unsigned*)(nh + hb_e), hp,
                               __ATOMIC_RELAXED, __HIP_MEMORY_SCOPE_AGENT);
            __hip_atomic_store((unsigned*)(nh + 16384 + hb_e), lp,
                               __ATOMIC_RELAXED, __HIP_MEMORY_SCOPE_AGENT);
        }

        if (t < SEQ - 1) {
            // drain this wave's stores to the coherence point, then barrier:
            // after it, ALL waves' h stores are globally visible.
            asm volatile("s_waitcnt vmcnt(0)" ::: "memory");
            __syncthreads();
            if (tid == 0)
                __hip_atomic_store(&flags[bid * 16], (unsigned)(t + 1),
                                   __ATOMIC_RELAXED, __HIP_MEMORY_SCOPE_AGENT);
            if (tid < 64) {
                const unsigned tgt = (unsigned)(t + 1);
                while (true) {
                    unsigned v = __hip_atomic_load(&flags[tid * 16],
                                                   __ATOMIC_RELAXED, __HIP_MEMORY_SCOPE_AGENT);
                    if (__all((int)(v >= tgt))) break;
                    __builtin_amdgcn_s_sleep(1);
                }
            }
            __builtin_amdgcn_sched_barrier(0);
            __syncthreads();
        }
    }
}

// ---------- K3: projection via bf16 hi/lo 3-pass MFMA (unchanged) ----------
__global__ void __launch_bounds__(256, 2) k_proj_mfma(
    const float* __restrict__ hsx,
    const float* __restrict__ Wc,
    const float* __restrict__ bc,
    float* __restrict__ out) {
    __shared__ unsigned short Ah[128 * 64], Al[128 * 64];
    __shared__ unsigned short Bh[128 * 64], Bl[128 * 64];

    const int tid = threadIdx.x;
    const int bid = blockIdx.x;
    const int swz = (bid & 7) * 500 + (bid >> 3);
    const int nt = swz / 16, mt = swz & 15;
    const int n0 = nt * 128;

    const int a_mrow = tid >> 4;
    const int a_k4   = (tid & 15) * 4;
    const int b_kb  = (tid >> 5) * 8;
    const int b_nb4 = (tid & 31) * 4;

    const int lane = tid & 63;
    const int w    = tid >> 6;
    const int wm   = (w >> 1) * 64;
    const int wn   = (w & 1) * 64;
    const int lr   = lane & 15;
    const int kg   = lane >> 4;

    f32x4 acc[4][4];
#pragma unroll
    for (int i = 0; i < 4; ++i)
#pragma unroll
        for (int j = 0; j < 4; ++j) acc[i][j] = (f32x4){0.f, 0.f, 0.f, 0.f};

    float4 rawA[8], rawB[8];
#pragma unroll
    for (int p = 0; p < 8; ++p) {
        int ml = p * 16 + a_mrow;
        rawA[p] = *(const float4*)(hsx + ((size_t)(ml + 1) * BATCH + mt) * UNITS + a_k4);
    }
#pragma unroll
    for (int i = 0; i < 8; ++i)
        rawB[i] = *(const float4*)(Wc + (size_t)(b_kb + i) * VOCAB + n0 + b_nb4);

    for (int kt = 0; kt < 16; ++kt) {
        __syncthreads();
#pragma unroll
        for (int p = 0; p < 8; ++p) {
            int ml = p * 16 + a_mrow;
            float v[4] = {rawA[p].x, rawA[p].y, rawA[p].z, rawA[p].w};
            ushort4 h, l;
            unsigned short* hp = (unsigned short*)&h;
            unsigned short* lp = (unsigned short*)&l;
#pragma unroll
            for (int q = 0; q < 4; ++q) {
                unsigned short hb = bf16_rne(v[q]);
                hp[q] = hb;
                lp[q] = bf16_trunc(v[q] - bf16_f32(hb));
            }
            int e = swz_e(ml, a_k4);
            *(ushort4*)(&Ah[e]) = h;
            *(ushort4*)(&Al[e]) = l;
        }
#pragma unroll
        for (int nn = 0; nn < 4; ++nn) {
            unsigned short h8[8], l8[8];
#pragma unroll
            for (int i = 0; i < 8; ++i) {
                float v = ((const float*)&rawB[i])[nn];
                unsigned short hb = bf16_rne(v);
                h8[i] = hb;
                l8[i] = bf16_trunc(v - bf16_f32(hb));
            }
            int e = swz_e(b_nb4 + nn, b_kb);
            *(s16x8*)(&Bh[e]) = *(const s16x8*)h8;
            *(s16x8*)(&Bl[e]) = *(const s16x8*)l8;
        }
        __syncthreads();
        if (kt < 15) {
            const int k0n = (kt + 1) * 64;
#pragma unroll
            for (int p = 0; p < 8; ++p) {
                int ml = p * 16 + a_mrow;
                rawA[p] = *(const float4*)(hsx + ((size_t)(ml + 1) * BATCH + mt) * UNITS + k0n + a_k4);
            }
#pragma unroll
            for (int i = 0; i < 8; ++i)
                rawB[i] = *(const float4*)(Wc + (size_t)(k0n + b_kb + i) * VOCAB + n0 + b_nb4);
        }
#pragma unroll
        for (int ks = 0; ks < 2; ++ks) {
            const int kofs = ks * 32 + kg * 8;
            s16x8 ah[4], al[4], bh[4], bl[4];
#pragma unroll
            for (int mi = 0; mi < 4; ++mi) {
                int e = swz_e(wm + mi * 16 + lr, kofs);
                ah[mi] = *(const s16x8*)(&Ah[e]);
                al[mi] = *(const s16x8*)(&Al[e]);
            }
#pragma unroll
            for (int ni = 0; ni < 4; ++ni) {
                int e = swz_e(wn + ni * 16 + lr, kofs);
                bh[ni] = *(const s16x8*)(&Bh[e]);
                bl[ni] = *(const s16x8*)(&Bl[e]);
            }
#pragma unroll
            for (int mi = 0; mi < 4; ++mi)
#pragma unroll
                for (int ni = 0; ni < 4; ++ni) {
                    acc[mi][ni] = __builtin_amdgcn_mfma_f32_16x16x32_bf16(ah[mi], bh[ni], acc[mi][ni], 0, 0, 0);
                    acc[mi][ni] = __builtin_amdgcn_mfma_f32_16x16x32_bf16(ah[mi], bl[ni], acc[mi][ni], 0, 0, 0);
                    acc[mi][ni] = __builtin_amdgcn_mfma_f32_16x16x32_bf16(al[mi], bh[ni], acc[mi][ni], 0, 0, 0);
                }
        }
    }

    float bcv[4];
#pragma unroll
    for (int ni = 0; ni < 4; ++ni) bcv[ni] = bc[n0 + wn + ni * 16 + lr];
#pragma unroll
    for (int mi = 0; mi < 4; ++mi) {
#pragma unroll
        for (int ni = 0; ni < 4; ++ni) {
#pragma unroll
            for (int r = 0; r < 4; ++r) {
                int grow = mt * 128 + wm + mi * 16 + kg * 4 + r;
                int gcol = n0 + wn + ni * 16 + lr;
                out[(size_t)grow * VOCAB + gcol] = acc[mi][ni][r] + bcv[ni];
            }
        }
    }
}

extern "C" void kernel_launch(void* const* d_in, const int* in_sizes, int n_in,
                              void* d_out, int out_size, void* d_ws, size_t ws_size,
                              hipStream_t stream) {
    const int*   inputs = (const int*)d_in[0];   // int32 (JAX x64 disabled)
    const float* emb  = (const float*)d_in[1];
    const float* W    = (const float*)d_in[2];
    const float* U    = (const float*)d_in[3];
    const float* bias = (const float*)d_in[4];
    const float* Wc   = (const float*)d_in[5];
    const float* bc   = (const float*)d_in[6];
    float* out = (float*)d_out;

    char* ws = (char*)d_ws;
    float*          xWb   = (float*)(ws + 0);
    float*          hsx   = (float*)(ws + 33554432);
    unsigned short* ub_hi = (unsigned short*)(ws + 42008576);
    unsigned short* ub_lo = (unsigned short*)(ws + 50397184);
    unsigned short* hb    = (unsigned short*)(ws + 58785792);
    unsigned*       flags = (unsigned*)(ws + 58916864);

    // h0 = 0 (f32 + bf16 buffers), barrier flags = 0 — every call
    hipMemsetAsync(hsx, 0, (size_t)BATCH * UNITS * 4, stream);
    hipMemsetAsync(hb,  0, 65536, stream);
    hipMemsetAsync(flags, 0, 4096, stream);

    k_prep_ub<<<256, 256, 0, stream>>>(U, ub_hi, ub_lo);
    k_embed_xw<<<dim3(16, 128), 256, 0, stream>>>(inputs, emb, W, bias, xWb);
    k_lstm_all<<<NB, 256, 0, stream>>>(ub_hi, ub_lo, xWb, hsx, hb, flags);
    k_proj_mfma<<<4000, 256, 0, stream>>>(hsx, Wc, bc, out);
}